// Round 6
// baseline (323.787 us; speedup 1.0000x reference)
//
#include <hip/hip_runtime.h>

#define SEQ 2048
#define DMODEL 1024
#define NH 16
#define HD 64

typedef unsigned short bf16u;
typedef unsigned short u16x8 __attribute__((ext_vector_type(8)));
typedef unsigned short u16x4 __attribute__((ext_vector_type(4)));
typedef float f32x4 __attribute__((ext_vector_type(4)));

__device__ __forceinline__ unsigned short f2b(float f) {
  __bf16 h = (__bf16)f;
  return __builtin_bit_cast(unsigned short, h);
}

__device__ __forceinline__ f32x4 mfma_bf16(u16x8 a, u16x8 b, f32x4 c) {
  return __builtin_amdgcn_mfma_f32_16x16x32_bf16(a, b, c, 0, 0, 0);
}

// async 16B global -> LDS (lane i of the wave lands at ldsbase + i*16)
__device__ __forceinline__ void load16_lds(const bf16u* g, bf16u* l) {
  __builtin_amdgcn_global_load_lds(
      (const __attribute__((address_space(1))) unsigned int*)(const void*)g,
      (__attribute__((address_space(3))) unsigned int*)(void*)l, 16, 0, 0);
}

// ---------------- cast x (fp32 -> bf16) ----------------
__global__ __launch_bounds__(256) void cast_x_kernel(const float4* __restrict__ x,
                                                     u16x4* __restrict__ xb, int n4) {
  int i = blockIdx.x * blockDim.x + threadIdx.x;
  if (i < n4) {
    float4 v = x[i];
    u16x4 o;
    o[0] = f2b(v.x); o[1] = f2b(v.y); o[2] = f2b(v.z); o[3] = f2b(v.w);
    xb[i] = o;
  }
}

// ---------------- weight transpose + cast: W[k][n] fp32 -> Wt[n][k] bf16 ----------------
__global__ __launch_bounds__(256) void transpose_w_kernel(const float* __restrict__ W0,
                                                          const float* __restrict__ W1,
                                                          const float* __restrict__ W2,
                                                          const float* __restrict__ W3,
                                                          bf16u* __restrict__ T) {
  const float* W = (blockIdx.z == 0) ? W0 : (blockIdx.z == 1) ? W1
                  : (blockIdx.z == 2) ? W2 : W3;
  bf16u* Wt = T + (size_t)blockIdx.z * (DMODEL * DMODEL);
  __shared__ float tile[32][33];
  int n = blockIdx.x * 32 + threadIdx.x;
  int k0 = blockIdx.y * 32;
  for (int i = threadIdx.y; i < 32; i += 8)
    tile[i][threadIdx.x] = W[(size_t)(k0 + i) * DMODEL + n];
  __syncthreads();
  int k = k0 + threadIdx.x;
  int n0 = blockIdx.x * 32;
  for (int i = threadIdx.y; i < 32; i += 8)
    Wt[(size_t)(n0 + i) * DMODEL + k] = f2b(tile[threadIdx.x][i]);
}

// ================= shared GEMM notes =================
// LDS tile: rows x 32 cols bf16, stride 32, 16B blocks XOR-swizzled:
// row r block b at slot (b ^ (r&3)); frag reads use xq = (quad ^ (l15&3))*8.
// 2-way bank aliasing only (free per m136).

// ---------------- 128x128 bf16 MFMA GEMM, QKV variant ----------------
// Q out is PRE-SCALED by 0.125*log2(e) (attention softmax scale folded in).
// Q,K out: [b][h][s][hd] bf16;  V out: [b][h][hd][s] bf16 (pre-transposed).
__global__ __launch_bounds__(256) void gemm_qkv_kernel(const bf16u* __restrict__ A,
                                                       const bf16u* __restrict__ Wt,
                                                       bf16u* __restrict__ QKV) {
  const bf16u* Bt = Wt + (size_t)blockIdx.z * (DMODEL * DMODEL);
  bf16u* O = QKV + (size_t)blockIdx.z * ((size_t)8192 * DMODEL);
  const bool vmode = (blockIdx.z == 2);
  const float smul = (blockIdx.z == 0) ? 0.18033688f : 1.0f;  // 0.125*log2(e) into Q

  __shared__ __align__(16) bf16u As[128 * 32];
  __shared__ __align__(16) bf16u Bs[128 * 32];

  const int tid = threadIdx.x;
  const int lane = tid & 63, quad = lane >> 4, l15 = lane & 15;
  const int wave = tid >> 6;
  const int wrow = (wave >> 1) * 64, wcol = (wave & 1) * 64;
  const int mbase = blockIdx.y * 128, nbase = blockIdx.x * 128;

  const int r0 = tid >> 2, s0 = tid & 3;
  const int g0 = s0 ^ (r0 & 3);
  const bf16u* Ag0 = A + (size_t)(mbase + r0) * DMODEL + g0 * 8;
  const bf16u* Bg0 = Bt + (size_t)(nbase + r0) * DMODEL + g0 * 8;
  const bf16u* Ag1 = Ag0 + (size_t)64 * DMODEL;
  const bf16u* Bg1 = Bg0 + (size_t)64 * DMODEL;
  bf16u* Al0 = &As[tid * 8];
  bf16u* Al1 = &As[2048 + tid * 8];
  bf16u* Bl0 = &Bs[tid * 8];
  bf16u* Bl1 = &Bs[2048 + tid * 8];

  const int xq = (quad ^ (l15 & 3)) * 8;

  f32x4 acc[4][4];
#pragma unroll
  for (int i = 0; i < 4; ++i)
#pragma unroll
    for (int j = 0; j < 4; ++j) acc[i][j] = (f32x4){0.f, 0.f, 0.f, 0.f};

  for (int k0 = 0; k0 < DMODEL; k0 += 32) {
    __syncthreads();
    load16_lds(Ag0 + k0, Al0);
    load16_lds(Ag1 + k0, Al1);
    load16_lds(Bg0 + k0, Bl0);
    load16_lds(Bg1 + k0, Bl1);
    __syncthreads();
    u16x8 af[4], bfr[4];
#pragma unroll
    for (int i = 0; i < 4; ++i)
      af[i] = *(const u16x8*)&As[(wrow + i * 16 + l15) * 32 + xq];
#pragma unroll
    for (int j = 0; j < 4; ++j)
      bfr[j] = *(const u16x8*)&Bs[(wcol + j * 16 + l15) * 32 + xq];
#pragma unroll
    for (int i = 0; i < 4; ++i)
#pragma unroll
      for (int j = 0; j < 4; ++j)
        acc[i][j] = mfma_bf16(af[i], bfr[j], acc[i][j]);
  }

#pragma unroll
  for (int i = 0; i < 4; ++i) {
    const int mrow = mbase + wrow + i * 16 + quad * 4;
    const int bb = mrow >> 11, ss = mrow & 2047;
#pragma unroll
    for (int j = 0; j < 4; ++j) {
      const int n = nbase + wcol + j * 16 + l15;
      const int h = n >> 6, hd = n & 63;
      if (vmode) {
        u16x4 pk;
#pragma unroll
        for (int r = 0; r < 4; ++r) pk[r] = f2b(acc[i][j][r]);
        *(u16x4*)&O[(((size_t)(bb * NH + h)) * HD + hd) * SEQ + ss] = pk;
      } else {
#pragma unroll
        for (int r = 0; r < 4; ++r)
          O[(((size_t)(bb * NH + h)) * SEQ + ss + r) * HD + hd] = f2b(acc[i][j][r] * smul);
      }
    }
  }
}

// ---------------- 64x128 bf16 MFMA GEMM, fp32-output variant ----------------
__global__ __launch_bounds__(256, 2) void gemm_out_kernel(const bf16u* __restrict__ A,
                                                          const bf16u* __restrict__ Bt,
                                                          float* __restrict__ Of) {
  __shared__ __align__(16) bf16u As[64 * 32];
  __shared__ __align__(16) bf16u Bs[128 * 32];

  const int tid = threadIdx.x;
  const int lane = tid & 63, quad = lane >> 4, l15 = lane & 15;
  const int wave = tid >> 6;
  const int wrow = (wave >> 1) * 32, wcol = (wave & 1) * 64;
  const int mbase = blockIdx.y * 64, nbase = blockIdx.x * 128;

  const int r0 = tid >> 2, s0 = tid & 3;
  const int g0 = s0 ^ (r0 & 3);
  const bf16u* Ag0 = A + (size_t)(mbase + r0) * DMODEL + g0 * 8;
  const bf16u* Bg0 = Bt + (size_t)(nbase + r0) * DMODEL + g0 * 8;
  const bf16u* Bg1 = Bg0 + (size_t)64 * DMODEL;
  bf16u* Al0 = &As[tid * 8];
  bf16u* Bl0 = &Bs[tid * 8];
  bf16u* Bl1 = &Bs[2048 + tid * 8];

  const int xq = (quad ^ (l15 & 3)) * 8;

  f32x4 acc[2][4];
#pragma unroll
  for (int i = 0; i < 2; ++i)
#pragma unroll
    for (int j = 0; j < 4; ++j) acc[i][j] = (f32x4){0.f, 0.f, 0.f, 0.f};

  for (int k0 = 0; k0 < DMODEL; k0 += 32) {
    __syncthreads();
    load16_lds(Ag0 + k0, Al0);
    load16_lds(Bg0 + k0, Bl0);
    load16_lds(Bg1 + k0, Bl1);
    __syncthreads();
    u16x8 af[2], bfr[4];
#pragma unroll
    for (int i = 0; i < 2; ++i)
      af[i] = *(const u16x8*)&As[(wrow + i * 16 + l15) * 32 + xq];
#pragma unroll
    for (int j = 0; j < 4; ++j)
      bfr[j] = *(const u16x8*)&Bs[(wcol + j * 16 + l15) * 32 + xq];
#pragma unroll
    for (int i = 0; i < 2; ++i)
#pragma unroll
      for (int j = 0; j < 4; ++j)
        acc[i][j] = mfma_bf16(af[i], bfr[j], acc[i][j]);
  }

#pragma unroll
  for (int i = 0; i < 2; ++i) {
    const int mrow = mbase + wrow + i * 16 + quad * 4;
#pragma unroll
    for (int j = 0; j < 4; ++j) {
      const int n = nbase + wcol + j * 16 + l15;
#pragma unroll
      for (int r = 0; r < 4; ++r)
        Of[(size_t)(mrow + r) * DMODEL + n] = acc[i][j][r];
    }
  }
}

// ---------------- flash attention (causal), bf16 MFMA, v6 ----------------
// v5 structure (one 128-row q-tile/block, grid (16,B*NH) heaviest-first,
// 27.1 KB LDS) but WITHOUT the VGPR cap: (256,2) -> ~84 VGPRs, no scratch
// spills (v5's (256,4)=64 VGPRs spilled: WRITE_SIZE 16384->22528 KB, dur 137us).
__global__ __launch_bounds__(256, 2) void attn_kernel(const bf16u* __restrict__ Q,
                                                      const bf16u* __restrict__ K,
                                                      const bf16u* __restrict__ Vt,
                                                      bf16u* __restrict__ ctx) {
  const int bh = blockIdx.y;
  const int b = bh >> 4, h = bh & 15;
  const int qt = 15 - blockIdx.x;  // heaviest causal blocks dispatch first
  const size_t base = (size_t)bh * SEQ * HD;
  const bf16u* Qb = Q + base;
  const bf16u* Kb = K + base;
  const bf16u* Vb = Vt + base;  // [hd][s]

  const int tid = threadIdx.x;
  const int wave = tid >> 6, lane = tid & 63, quad = lane >> 4, l15 = lane & 15;
  const int qrow0 = qt * 128 + wave * 32;
  const int ntiles = 2 * qt + 2;

  __shared__ __align__(16) bf16u Ks[64 * 72];     // [key][hd]
  __shared__ __align__(16) bf16u Vs[64 * 72];     // [hd][key]
  __shared__ __align__(16) bf16u Ps[4][16 * 68];  // per-wave 16-row P scratch

  const int srow = tid >> 3;       // 0..31
  const int scol = (tid & 7) * 8;  // 0..56

  u16x8 ones;
#pragma unroll
  for (int i = 0; i < 8; ++i) ones[i] = 0x3F80;  // bf16 1.0

  u16x8 aq[2][2];
#pragma unroll
  for (int rt = 0; rt < 2; ++rt)
#pragma unroll
    for (int ch = 0; ch < 2; ++ch)
      aq[rt][ch] = *(const u16x8*)(Qb + (size_t)(qrow0 + rt * 16 + l15) * HD + ch * 32 + quad * 8);

  f32x4 acc[2][4], accl[2];
#pragma unroll
  for (int rt = 0; rt < 2; ++rt) {
#pragma unroll
    for (int nc = 0; nc < 4; ++nc) acc[rt][nc] = (f32x4){0.f, 0.f, 0.f, 0.f};
    accl[rt] = (f32x4){0.f, 0.f, 0.f, 0.f};
  }

  u16x8 kr0 = *(const u16x8*)(Kb + (size_t)srow * HD + scol);
  u16x8 kr1 = *(const u16x8*)(Kb + (size_t)(srow + 32) * HD + scol);
  u16x8 vr0 = *(const u16x8*)(Vb + (size_t)srow * SEQ + scol);
  u16x8 vr1 = *(const u16x8*)(Vb + (size_t)(srow + 32) * SEQ + scol);

#pragma unroll 1
  for (int kt = 0; kt < ntiles; ++kt) {
    const int kbase = kt * 64;
    __syncthreads();
    *(u16x8*)&Ks[srow * 72 + scol] = kr0;
    *(u16x8*)&Ks[(srow + 32) * 72 + scol] = kr1;
    *(u16x8*)&Vs[srow * 72 + scol] = vr0;
    *(u16x8*)&Vs[(srow + 32) * 72 + scol] = vr1;
    __syncthreads();
    if (kt + 1 < ntiles) {
      const int nb = kbase + 64;
      kr0 = *(const u16x8*)(Kb + (size_t)(nb + srow) * HD + scol);
      kr1 = *(const u16x8*)(Kb + (size_t)(nb + srow + 32) * HD + scol);
      vr0 = *(const u16x8*)(Vb + (size_t)srow * SEQ + nb + scol);
      vr1 = *(const u16x8*)(Vb + (size_t)(srow + 32) * SEQ + nb + scol);
    }
    if (kbase > qrow0 + 31) continue;  // fully masked for this wave

    // QK^T: 32 rows x 64 keys (Q pre-scaled: scores are log2-domain ready)
    f32x4 sc[2][4];
#pragma unroll
    for (int ct = 0; ct < 4; ++ct) {
      u16x8 bk0 = *(const u16x8*)&Ks[(ct * 16 + l15) * 72 + quad * 8];
      u16x8 bk1 = *(const u16x8*)&Ks[(ct * 16 + l15) * 72 + 32 + quad * 8];
#pragma unroll
      for (int rt = 0; rt < 2; ++rt) {
        f32x4 z = {0.f, 0.f, 0.f, 0.f};
        z = mfma_bf16(aq[rt][0], bk0, z);
        z = mfma_bf16(aq[rt][1], bk1, z);
        sc[rt][ct] = z;
      }
    }

    const bool needmask = (kbase + 63 > qrow0);
    u16x8 pa[2][2];
#pragma unroll
    for (int rt = 0; rt < 2; ++rt) {
#pragma unroll
      for (int r = 0; r < 4; ++r) {
        const int row = qrow0 + rt * 16 + quad * 4 + r;
        float e0 = exp2f(sc[rt][0][r]);
        float e1 = exp2f(sc[rt][1][r]);
        float e2 = exp2f(sc[rt][2][r]);
        float e3 = exp2f(sc[rt][3][r]);
        if (needmask) {
          if (kbase + l15 > row) e0 = 0.f;
          if (kbase + 16 + l15 > row) e1 = 0.f;
          if (kbase + 32 + l15 > row) e2 = 0.f;
          if (kbase + 48 + l15 > row) e3 = 0.f;
        }
        const int prow = (quad * 4 + r) * 68;
        Ps[wave][prow + l15] = f2b(e0);
        Ps[wave][prow + 16 + l15] = f2b(e1);
        Ps[wave][prow + 32 + l15] = f2b(e2);
        Ps[wave][prow + 48 + l15] = f2b(e3);
      }
      // same-wave LDS write->read: in-order per wave, compiler inserts lgkmcnt
      pa[rt][0] = *(const u16x8*)&Ps[wave][l15 * 68 + quad * 8];
      pa[rt][1] = *(const u16x8*)&Ps[wave][l15 * 68 + 32 + quad * 8];
    }

#pragma unroll
    for (int nc = 0; nc < 4; ++nc) {
      u16x8 bv0 = *(const u16x8*)&Vs[(nc * 16 + l15) * 72 + quad * 8];
      u16x8 bv1 = *(const u16x8*)&Vs[(nc * 16 + l15) * 72 + 32 + quad * 8];
#pragma unroll
      for (int rt = 0; rt < 2; ++rt) {
        acc[rt][nc] = mfma_bf16(pa[rt][0], bv0, acc[rt][nc]);
        acc[rt][nc] = mfma_bf16(pa[rt][1], bv1, acc[rt][nc]);
      }
    }
#pragma unroll
    for (int rt = 0; rt < 2; ++rt) {
      accl[rt] = mfma_bf16(pa[rt][0], ones, accl[rt]);
      accl[rt] = mfma_bf16(pa[rt][1], ones, accl[rt]);
    }
  }

  // epilogue: normalize, write ctx[b][s][h*64+hd] bf16
#pragma unroll
  for (int rt = 0; rt < 2; ++rt) {
#pragma unroll
    for (int r = 0; r < 4; ++r) {
      const float inv = 1.0f / accl[rt][r];
      const int row = qrow0 + rt * 16 + quad * 4 + r;
      const size_t o = ((size_t)b * SEQ + row) * DMODEL + h * HD;
#pragma unroll
      for (int nc = 0; nc < 4; ++nc)
        ctx[o + nc * 16 + l15] = f2b(acc[rt][nc][r] * inv);
    }
  }
}

extern "C" void kernel_launch(void* const* d_in, const int* in_sizes, int n_in,
                              void* d_out, int out_size, void* d_ws, size_t ws_size,
                              hipStream_t stream) {
  const float* x  = (const float*)d_in[0];
  const float* Wq = (const float*)d_in[1];
  const float* Wk = (const float*)d_in[2];
  const float* Wv = (const float*)d_in[3];
  const float* Wo = (const float*)d_in[4];
  float* out = (float*)d_out;

  char* ws = (char*)d_ws;
  const size_t MK = (size_t)8192 * DMODEL;
  const size_t WW = (size_t)DMODEL * DMODEL;
  bf16u* xb  = (bf16u*)ws;
  bf16u* Wt  = (bf16u*)(ws + MK * 2);
  bf16u* QKV = (bf16u*)(ws + MK * 2 + 4 * WW * 2);
  bf16u* Cx  = (bf16u*)(ws + MK * 2 + 4 * WW * 2 + 3 * MK * 2);

  const int n4 = (int)(MK / 4);
  cast_x_kernel<<<dim3(n4 / 256), 256, 0, stream>>>((const float4*)x, (u16x4*)xb, n4);
  transpose_w_kernel<<<dim3(32, 32, 4), dim3(32, 8), 0, stream>>>(Wq, Wk, Wv, Wo, Wt);
  gemm_qkv_kernel<<<dim3(8, 64, 3), 256, 0, stream>>>(xb, Wt, QKV);
  attn_kernel<<<dim3(16, 64), 256, 0, stream>>>(QKV, QKV + MK, QKV + 2 * MK, Cx);
  gemm_out_kernel<<<dim3(8, 128), 256, 0, stream>>>(Cx, Wt + 3 * WW, out);
}

// Round 7
// 274.036 us; speedup vs baseline: 1.1815x; 1.1815x over previous
//
#include <hip/hip_runtime.h>

#define SEQ 2048
#define DMODEL 1024
#define NH 16
#define HD 64

typedef unsigned short bf16u;
typedef unsigned short u16x8 __attribute__((ext_vector_type(8)));
typedef unsigned short u16x4 __attribute__((ext_vector_type(4)));
typedef float f32x4 __attribute__((ext_vector_type(4)));

__device__ __forceinline__ unsigned short f2b(float f) {
  __bf16 h = (__bf16)f;
  return __builtin_bit_cast(unsigned short, h);
}

__device__ __forceinline__ f32x4 mfma_bf16(u16x8 a, u16x8 b, f32x4 c) {
  return __builtin_amdgcn_mfma_f32_16x16x32_bf16(a, b, c, 0, 0, 0);
}

// async 16B global -> LDS (lane i of the wave lands at ldsbase + i*16)
__device__ __forceinline__ void load16_lds(const bf16u* g, bf16u* l) {
  __builtin_amdgcn_global_load_lds(
      (const __attribute__((address_space(1))) unsigned int*)(const void*)g,
      (__attribute__((address_space(3))) unsigned int*)(void*)l, 16, 0, 0);
}

// s_waitcnt imm (gfx9): vmcnt[3:0] | expcnt[6:4] | lgkmcnt[11:8]
#define WAITCNT_VM(n) __builtin_amdgcn_s_waitcnt(0x0F70 | (n))

// ---------------- cast x (fp32 -> bf16) ----------------
__global__ __launch_bounds__(256) void cast_x_kernel(const float4* __restrict__ x,
                                                     u16x4* __restrict__ xb, int n4) {
  int i = blockIdx.x * blockDim.x + threadIdx.x;
  if (i < n4) {
    float4 v = x[i];
    u16x4 o;
    o[0] = f2b(v.x); o[1] = f2b(v.y); o[2] = f2b(v.z); o[3] = f2b(v.w);
    xb[i] = o;
  }
}

// ---------------- weight transpose + cast: W[k][n] fp32 -> Wt[n][k] bf16 ----------------
__global__ __launch_bounds__(256) void transpose_w_kernel(const float* __restrict__ W0,
                                                          const float* __restrict__ W1,
                                                          const float* __restrict__ W2,
                                                          const float* __restrict__ W3,
                                                          bf16u* __restrict__ T) {
  const float* W = (blockIdx.z == 0) ? W0 : (blockIdx.z == 1) ? W1
                  : (blockIdx.z == 2) ? W2 : W3;
  bf16u* Wt = T + (size_t)blockIdx.z * (DMODEL * DMODEL);
  __shared__ float tile[32][33];
  int n = blockIdx.x * 32 + threadIdx.x;
  int k0 = blockIdx.y * 32;
  for (int i = threadIdx.y; i < 32; i += 8)
    tile[i][threadIdx.x] = W[(size_t)(k0 + i) * DMODEL + n];
  __syncthreads();
  int k = k0 + threadIdx.x;
  int n0 = blockIdx.x * 32;
  for (int i = threadIdx.y; i < 32; i += 8)
    Wt[(size_t)(n0 + i) * DMODEL + k] = f2b(tile[threadIdx.x][i]);
}

// ================= shared GEMM notes =================
// LDS tile: rows x 32 cols bf16, 16B blocks XOR-swizzled (slot = b ^ (r&3));
// frag reads use xq = (quad ^ (l15&3))*8 -> 2-way bank aliasing only (free).
// Pipelined K-loop: double-buffered LDS; per iter: issue DMA for k+1 into nxt,
// s_waitcnt vmcnt(#nxt-loads) so THIS wave's cur-set is done, raw s_barrier
// (every wave drained its own cur-set before rendezvous -> tile published),
// compute cur. Trailing barrier guards nxt against overwrite-while-read.

// ---------------- 128x128 bf16 MFMA GEMM, QKV variant ----------------
// Q out PRE-SCALED by 0.125*log2(e). Q,K: [b][h][s][hd]; V: [b][h][hd][s].
__global__ __launch_bounds__(256) void gemm_qkv_kernel(const bf16u* __restrict__ A,
                                                       const bf16u* __restrict__ Wt,
                                                       bf16u* __restrict__ QKV) {
  const bf16u* Bt = Wt + (size_t)blockIdx.z * (DMODEL * DMODEL);
  bf16u* O = QKV + (size_t)blockIdx.z * ((size_t)8192 * DMODEL);
  const bool vmode = (blockIdx.z == 2);
  const float smul = (blockIdx.z == 0) ? 0.18033688f : 1.0f;

  __shared__ __align__(16) bf16u As[2][128 * 32];
  __shared__ __align__(16) bf16u Bs[2][128 * 32];

  const int tid = threadIdx.x;
  const int lane = tid & 63, quad = lane >> 4, l15 = lane & 15;
  const int wave = tid >> 6;
  const int wrow = (wave >> 1) * 64, wcol = (wave & 1) * 64;
  const int mbase = blockIdx.y * 128, nbase = blockIdx.x * 128;

  const int r0 = tid >> 2, s0 = tid & 3;
  const int g0 = s0 ^ (r0 & 3);
  const bf16u* Ag0 = A + (size_t)(mbase + r0) * DMODEL + g0 * 8;
  const bf16u* Bg0 = Bt + (size_t)(nbase + r0) * DMODEL + g0 * 8;
  const bf16u* Ag1 = Ag0 + (size_t)64 * DMODEL;
  const bf16u* Bg1 = Bg0 + (size_t)64 * DMODEL;

  const int xq = (quad ^ (l15 & 3)) * 8;

  f32x4 acc[4][4];
#pragma unroll
  for (int i = 0; i < 4; ++i)
#pragma unroll
    for (int j = 0; j < 4; ++j) acc[i][j] = (f32x4){0.f, 0.f, 0.f, 0.f};

  // prologue: stage k-slice 0 into buffer 0
  load16_lds(Ag0, &As[0][tid * 8]);
  load16_lds(Ag1, &As[0][2048 + tid * 8]);
  load16_lds(Bg0, &Bs[0][tid * 8]);
  load16_lds(Bg1, &Bs[0][2048 + tid * 8]);

#pragma unroll 1
  for (int it = 0; it < 32; ++it) {
    const int cur = it & 1, nxt = cur ^ 1;
    if (it + 1 < 32) {
      const int kn = (it + 1) * 32;
      load16_lds(Ag0 + kn, &As[nxt][tid * 8]);
      load16_lds(Ag1 + kn, &As[nxt][2048 + tid * 8]);
      load16_lds(Bg0 + kn, &Bs[nxt][tid * 8]);
      load16_lds(Bg1 + kn, &Bs[nxt][2048 + tid * 8]);
      WAITCNT_VM(4);  // my cur-set done; nxt-set stays in flight
    } else {
      WAITCNT_VM(0);
    }
    __builtin_amdgcn_s_barrier();  // publish cur tile (no vmcnt(0) drain)
    u16x8 af[4], bfr[4];
#pragma unroll
    for (int i = 0; i < 4; ++i)
      af[i] = *(const u16x8*)&As[cur][(wrow + i * 16 + l15) * 32 + xq];
#pragma unroll
    for (int j = 0; j < 4; ++j)
      bfr[j] = *(const u16x8*)&Bs[cur][(wcol + j * 16 + l15) * 32 + xq];
#pragma unroll
    for (int i = 0; i < 4; ++i)
#pragma unroll
      for (int j = 0; j < 4; ++j)
        acc[i][j] = mfma_bf16(af[i], bfr[j], acc[i][j]);
    __builtin_amdgcn_s_barrier();  // all waves done reading cur before it's re-filled
  }

#pragma unroll
  for (int i = 0; i < 4; ++i) {
    const int mrow = mbase + wrow + i * 16 + quad * 4;
    const int bb = mrow >> 11, ss = mrow & 2047;
#pragma unroll
    for (int j = 0; j < 4; ++j) {
      const int n = nbase + wcol + j * 16 + l15;
      const int h = n >> 6, hd = n & 63;
      if (vmode) {
        u16x4 pk;
#pragma unroll
        for (int r = 0; r < 4; ++r) pk[r] = f2b(acc[i][j][r]);
        *(u16x4*)&O[(((size_t)(bb * NH + h)) * HD + hd) * SEQ + ss] = pk;
      } else {
#pragma unroll
        for (int r = 0; r < 4; ++r)
          O[(((size_t)(bb * NH + h)) * SEQ + ss + r) * HD + hd] = f2b(acc[i][j][r] * smul);
      }
    }
  }
}

// ---------------- 128x128 bf16 MFMA GEMM, fp32-output, pipelined ----------------
__global__ __launch_bounds__(256) void gemm_out_kernel(const bf16u* __restrict__ A,
                                                       const bf16u* __restrict__ Bt,
                                                       float* __restrict__ Of) {
  __shared__ __align__(16) bf16u As[2][128 * 32];
  __shared__ __align__(16) bf16u Bs[2][128 * 32];

  const int tid = threadIdx.x;
  const int lane = tid & 63, quad = lane >> 4, l15 = lane & 15;
  const int wave = tid >> 6;
  const int wrow = (wave >> 1) * 64, wcol = (wave & 1) * 64;
  const int mbase = blockIdx.y * 128, nbase = blockIdx.x * 128;

  const int r0 = tid >> 2, s0 = tid & 3;
  const int g0 = s0 ^ (r0 & 3);
  const bf16u* Ag0 = A + (size_t)(mbase + r0) * DMODEL + g0 * 8;
  const bf16u* Bg0 = Bt + (size_t)(nbase + r0) * DMODEL + g0 * 8;
  const bf16u* Ag1 = Ag0 + (size_t)64 * DMODEL;
  const bf16u* Bg1 = Bg0 + (size_t)64 * DMODEL;

  const int xq = (quad ^ (l15 & 3)) * 8;

  f32x4 acc[4][4];
#pragma unroll
  for (int i = 0; i < 4; ++i)
#pragma unroll
    for (int j = 0; j < 4; ++j) acc[i][j] = (f32x4){0.f, 0.f, 0.f, 0.f};

  load16_lds(Ag0, &As[0][tid * 8]);
  load16_lds(Ag1, &As[0][2048 + tid * 8]);
  load16_lds(Bg0, &Bs[0][tid * 8]);
  load16_lds(Bg1, &Bs[0][2048 + tid * 8]);

#pragma unroll 1
  for (int it = 0; it < 32; ++it) {
    const int cur = it & 1, nxt = cur ^ 1;
    if (it + 1 < 32) {
      const int kn = (it + 1) * 32;
      load16_lds(Ag0 + kn, &As[nxt][tid * 8]);
      load16_lds(Ag1 + kn, &As[nxt][2048 + tid * 8]);
      load16_lds(Bg0 + kn, &Bs[nxt][tid * 8]);
      load16_lds(Bg1 + kn, &Bs[nxt][2048 + tid * 8]);
      WAITCNT_VM(4);
    } else {
      WAITCNT_VM(0);
    }
    __builtin_amdgcn_s_barrier();
    u16x8 af[4], bfr[4];
#pragma unroll
    for (int i = 0; i < 4; ++i)
      af[i] = *(const u16x8*)&As[cur][(wrow + i * 16 + l15) * 32 + xq];
#pragma unroll
    for (int j = 0; j < 4; ++j)
      bfr[j] = *(const u16x8*)&Bs[cur][(wcol + j * 16 + l15) * 32 + xq];
#pragma unroll
    for (int i = 0; i < 4; ++i)
#pragma unroll
      for (int j = 0; j < 4; ++j)
        acc[i][j] = mfma_bf16(af[i], bfr[j], acc[i][j]);
    __builtin_amdgcn_s_barrier();
  }

#pragma unroll
  for (int i = 0; i < 4; ++i) {
    const int mrow = mbase + wrow + i * 16 + quad * 4;
#pragma unroll
    for (int j = 0; j < 4; ++j) {
      const int n = nbase + wcol + j * 16 + l15;
#pragma unroll
      for (int r = 0; r < 4; ++r)
        Of[(size_t)(mrow + r) * DMODEL + n] = acc[i][j][r];
    }
  }
}

// ---------------- flash attention (causal), bf16 MFMA, v7 = v4 structure ----------------
// Paired q-tiles {15-p, p}: uniform 34 tile-units/block (grid (8, B*NH), 512 blocks).
// CU-aliasing note: with one tile per block and grid.x=16, CU c only ever sees
// x = c mod 16 -> 16x static imbalance (v5/v6 regression). Pairing fixes it.
// No running max; Q pre-scaled; row sums via MFMA ones-column; no shuffles.
__global__ __launch_bounds__(256, 2) void attn_kernel(const bf16u* __restrict__ Q,
                                                      const bf16u* __restrict__ K,
                                                      const bf16u* __restrict__ Vt,
                                                      bf16u* __restrict__ ctx) {
  const int bh = blockIdx.y;
  const int b = bh >> 4, h = bh & 15;
  const int bp = blockIdx.x;  // 0..7
  const size_t base = (size_t)bh * SEQ * HD;
  const bf16u* Qb = Q + base;
  const bf16u* Kb = K + base;
  const bf16u* Vb = Vt + base;  // [hd][s]

  const int tid = threadIdx.x;
  const int wave = tid >> 6, lane = tid & 63, quad = lane >> 4, l15 = lane & 15;

  __shared__ __align__(16) bf16u Ks[64 * 72];     // [key][hd]
  __shared__ __align__(16) bf16u Vs[64 * 72];     // [hd][key]
  __shared__ __align__(16) bf16u Ps[4][32 * 68];  // per-wave P scratch

  const int srow = tid >> 3;       // 0..31
  const int scol = (tid & 7) * 8;  // 0..56

  u16x8 ones;
#pragma unroll
  for (int i = 0; i < 8; ++i) ones[i] = 0x3F80;  // bf16 1.0

#pragma unroll 1
  for (int pi = 0; pi < 2; ++pi) {
    const int qt = pi ? bp : (15 - bp);
    const int qrow0 = qt * 128 + wave * 32;
    const int ntiles = 2 * qt + 2;

    u16x8 aq[2][2];
#pragma unroll
    for (int rt = 0; rt < 2; ++rt)
#pragma unroll
      for (int ch = 0; ch < 2; ++ch)
        aq[rt][ch] = *(const u16x8*)(Qb + (size_t)(qrow0 + rt * 16 + l15) * HD + ch * 32 + quad * 8);

    f32x4 acc[2][4], accl[2];
#pragma unroll
    for (int rt = 0; rt < 2; ++rt) {
#pragma unroll
      for (int nc = 0; nc < 4; ++nc) acc[rt][nc] = (f32x4){0.f, 0.f, 0.f, 0.f};
      accl[rt] = (f32x4){0.f, 0.f, 0.f, 0.f};
    }

    u16x8 kr0 = *(const u16x8*)(Kb + (size_t)srow * HD + scol);
    u16x8 kr1 = *(const u16x8*)(Kb + (size_t)(srow + 32) * HD + scol);
    u16x8 vr0 = *(const u16x8*)(Vb + (size_t)srow * SEQ + scol);
    u16x8 vr1 = *(const u16x8*)(Vb + (size_t)(srow + 32) * SEQ + scol);

#pragma unroll 1
    for (int kt = 0; kt < ntiles; ++kt) {
      const int kbase = kt * 64;
      __syncthreads();
      *(u16x8*)&Ks[srow * 72 + scol] = kr0;
      *(u16x8*)&Ks[(srow + 32) * 72 + scol] = kr1;
      *(u16x8*)&Vs[srow * 72 + scol] = vr0;
      *(u16x8*)&Vs[(srow + 32) * 72 + scol] = vr1;
      __syncthreads();
      if (kt + 1 < ntiles) {
        const int nb = kbase + 64;
        kr0 = *(const u16x8*)(Kb + (size_t)(nb + srow) * HD + scol);
        kr1 = *(const u16x8*)(Kb + (size_t)(nb + srow + 32) * HD + scol);
        vr0 = *(const u16x8*)(Vb + (size_t)srow * SEQ + nb + scol);
        vr1 = *(const u16x8*)(Vb + (size_t)(srow + 32) * SEQ + nb + scol);
      }
      if (kbase > qrow0 + 31) continue;  // fully masked for this wave

      // QK^T: 32 rows x 64 keys (Q pre-scaled: scores log2-domain ready)
      f32x4 sc[2][4];
#pragma unroll
      for (int ct = 0; ct < 4; ++ct) {
        u16x8 bk0 = *(const u16x8*)&Ks[(ct * 16 + l15) * 72 + quad * 8];
        u16x8 bk1 = *(const u16x8*)&Ks[(ct * 16 + l15) * 72 + 32 + quad * 8];
#pragma unroll
        for (int rt = 0; rt < 2; ++rt) {
          f32x4 z = {0.f, 0.f, 0.f, 0.f};
          z = mfma_bf16(aq[rt][0], bk0, z);
          z = mfma_bf16(aq[rt][1], bk1, z);
          sc[rt][ct] = z;
        }
      }

      const bool needmask = (kbase + 63 > qrow0);
#pragma unroll
      for (int rt = 0; rt < 2; ++rt) {
#pragma unroll
        for (int r = 0; r < 4; ++r) {
          const int row = qrow0 + rt * 16 + quad * 4 + r;
          float e0 = exp2f(sc[rt][0][r]);
          float e1 = exp2f(sc[rt][1][r]);
          float e2 = exp2f(sc[rt][2][r]);
          float e3 = exp2f(sc[rt][3][r]);
          if (needmask) {
            if (kbase + l15 > row) e0 = 0.f;
            if (kbase + 16 + l15 > row) e1 = 0.f;
            if (kbase + 32 + l15 > row) e2 = 0.f;
            if (kbase + 48 + l15 > row) e3 = 0.f;
          }
          const int prow = (rt * 16 + quad * 4 + r) * 68;
          Ps[wave][prow + l15] = f2b(e0);
          Ps[wave][prow + 16 + l15] = f2b(e1);
          Ps[wave][prow + 32 + l15] = f2b(e2);
          Ps[wave][prow + 48 + l15] = f2b(e3);
        }
      }

      // P: C-layout -> LDS -> A-layout (same-wave readback, no barrier)
      u16x8 pa[2][2];
#pragma unroll
      for (int rt = 0; rt < 2; ++rt)
#pragma unroll
        for (int ch = 0; ch < 2; ++ch)
          pa[rt][ch] = *(const u16x8*)&Ps[wave][(rt * 16 + l15) * 68 + ch * 32 + quad * 8];

#pragma unroll
      for (int nc = 0; nc < 4; ++nc) {
        u16x8 bv0 = *(const u16x8*)&Vs[(nc * 16 + l15) * 72 + quad * 8];
        u16x8 bv1 = *(const u16x8*)&Vs[(nc * 16 + l15) * 72 + 32 + quad * 8];
#pragma unroll
        for (int rt = 0; rt < 2; ++rt) {
          acc[rt][nc] = mfma_bf16(pa[rt][0], bv0, acc[rt][nc]);
          acc[rt][nc] = mfma_bf16(pa[rt][1], bv1, acc[rt][nc]);
        }
      }
#pragma unroll
      for (int rt = 0; rt < 2; ++rt) {
        accl[rt] = mfma_bf16(pa[rt][0], ones, accl[rt]);
        accl[rt] = mfma_bf16(pa[rt][1], ones, accl[rt]);
      }
    }

    // epilogue: normalize, write ctx[b][s][h*64+hd] bf16
#pragma unroll
    for (int rt = 0; rt < 2; ++rt) {
#pragma unroll
      for (int r = 0; r < 4; ++r) {
        const float inv = 1.0f / accl[rt][r];
        const int row = qrow0 + rt * 16 + quad * 4 + r;
        const size_t o = ((size_t)b * SEQ + row) * DMODEL + h * HD;
#pragma unroll
        for (int nc = 0; nc < 4; ++nc)
          ctx[o + nc * 16 + l15] = f2b(acc[rt][nc][r] * inv);
      }
    }
  }
}

extern "C" void kernel_launch(void* const* d_in, const int* in_sizes, int n_in,
                              void* d_out, int out_size, void* d_ws, size_t ws_size,
                              hipStream_t stream) {
  const float* x  = (const float*)d_in[0];
  const float* Wq = (const float*)d_in[1];
  const float* Wk = (const float*)d_in[2];
  const float* Wv = (const float*)d_in[3];
  const float* Wo = (const float*)d_in[4];
  float* out = (float*)d_out;

  char* ws = (char*)d_ws;
  const size_t MK = (size_t)8192 * DMODEL;
  const size_t WW = (size_t)DMODEL * DMODEL;
  bf16u* xb  = (bf16u*)ws;
  bf16u* Wt  = (bf16u*)(ws + MK * 2);
  bf16u* QKV = (bf16u*)(ws + MK * 2 + 4 * WW * 2);
  bf16u* Cx  = (bf16u*)(ws + MK * 2 + 4 * WW * 2 + 3 * MK * 2);

  const int n4 = (int)(MK / 4);
  cast_x_kernel<<<dim3(n4 / 256), 256, 0, stream>>>((const float4*)x, (u16x4*)xb, n4);
  transpose_w_kernel<<<dim3(32, 32, 4), dim3(32, 8), 0, stream>>>(Wq, Wk, Wv, Wo, Wt);
  gemm_qkv_kernel<<<dim3(8, 64, 3), 256, 0, stream>>>(xb, Wt, QKV);
  attn_kernel<<<dim3(8, 64), 256, 0, stream>>>(QKV, QKV + MK, QKV + 2 * MK, Cx);
  gemm_out_kernel<<<dim3(8, 64), 256, 0, stream>>>(Cx, Wt + 3 * WW, out);
}

// Round 8
// 268.672 us; speedup vs baseline: 1.2051x; 1.0200x over previous
//
#include <hip/hip_runtime.h>

#define SEQ 2048
#define DMODEL 1024
#define NH 16
#define HD 64

typedef unsigned short bf16u;
typedef unsigned short u16x8 __attribute__((ext_vector_type(8)));
typedef unsigned short u16x4 __attribute__((ext_vector_type(4)));
typedef float f32x4 __attribute__((ext_vector_type(4)));

__device__ __forceinline__ unsigned short f2b(float f) {
  __bf16 h = (__bf16)f;
  return __builtin_bit_cast(unsigned short, h);
}

__device__ __forceinline__ f32x4 mfma_bf16(u16x8 a, u16x8 b, f32x4 c) {
  return __builtin_amdgcn_mfma_f32_16x16x32_bf16(a, b, c, 0, 0, 0);
}

// async 16B global -> LDS (lane i of the wave lands at ldsbase + i*16)
__device__ __forceinline__ void load16_lds(const bf16u* g, bf16u* l) {
  __builtin_amdgcn_global_load_lds(
      (const __attribute__((address_space(1))) unsigned int*)(const void*)g,
      (__attribute__((address_space(3))) unsigned int*)(void*)l, 16, 0, 0);
}

// s_waitcnt imm (gfx9): vmcnt[3:0] | expcnt[6:4] | lgkmcnt[11:8]
#define WAITCNT_VM(n) __builtin_amdgcn_s_waitcnt(0x0F70 | (n))

// ---------------- cast x (fp32 -> bf16) ----------------
__global__ __launch_bounds__(256) void cast_x_kernel(const float4* __restrict__ x,
                                                     u16x4* __restrict__ xb, int n4) {
  int i = blockIdx.x * blockDim.x + threadIdx.x;
  if (i < n4) {
    float4 v = x[i];
    u16x4 o;
    o[0] = f2b(v.x); o[1] = f2b(v.y); o[2] = f2b(v.z); o[3] = f2b(v.w);
    xb[i] = o;
  }
}

// ---------------- weight transpose + cast: W[k][n] fp32 -> Wt[n][k] bf16 ----------------
__global__ __launch_bounds__(256) void transpose_w_kernel(const float* __restrict__ W0,
                                                          const float* __restrict__ W1,
                                                          const float* __restrict__ W2,
                                                          const float* __restrict__ W3,
                                                          bf16u* __restrict__ T) {
  const float* W = (blockIdx.z == 0) ? W0 : (blockIdx.z == 1) ? W1
                  : (blockIdx.z == 2) ? W2 : W3;
  bf16u* Wt = T + (size_t)blockIdx.z * (DMODEL * DMODEL);
  __shared__ float tile[32][33];
  int n = blockIdx.x * 32 + threadIdx.x;
  int k0 = blockIdx.y * 32;
  for (int i = threadIdx.y; i < 32; i += 8)
    tile[i][threadIdx.x] = W[(size_t)(k0 + i) * DMODEL + n];
  __syncthreads();
  int k = k0 + threadIdx.x;
  int n0 = blockIdx.x * 32;
  for (int i = threadIdx.y; i < 32; i += 8)
    Wt[(size_t)(n0 + i) * DMODEL + k] = f2b(tile[threadIdx.x][i]);
}

// ================= shared GEMM notes =================
// LDS tile: rows x 32 cols bf16, 16B blocks XOR-swizzled (slot = b ^ (r&3));
// frag reads use xq = (quad ^ (l15&3))*8 -> 2-way bank aliasing only (free).

// ---------------- 128x128 bf16 MFMA GEMM, QKV variant ----------------
// Q out PRE-SCALED by 0.125*log2(e). Q,K: [b][h][s][hd]; V: [b][h][hd][s].
__global__ __launch_bounds__(256) void gemm_qkv_kernel(const bf16u* __restrict__ A,
                                                       const bf16u* __restrict__ Wt,
                                                       bf16u* __restrict__ QKV) {
  const bf16u* Bt = Wt + (size_t)blockIdx.z * (DMODEL * DMODEL);
  bf16u* O = QKV + (size_t)blockIdx.z * ((size_t)8192 * DMODEL);
  const bool vmode = (blockIdx.z == 2);
  const float smul = (blockIdx.z == 0) ? 0.18033688f : 1.0f;

  __shared__ __align__(16) bf16u As[2][128 * 32];
  __shared__ __align__(16) bf16u Bs[2][128 * 32];

  const int tid = threadIdx.x;
  const int lane = tid & 63, quad = lane >> 4, l15 = lane & 15;
  const int wave = tid >> 6;
  const int wrow = (wave >> 1) * 64, wcol = (wave & 1) * 64;
  const int mbase = blockIdx.y * 128, nbase = blockIdx.x * 128;

  const int r0 = tid >> 2, s0 = tid & 3;
  const int g0 = s0 ^ (r0 & 3);
  const bf16u* Ag0 = A + (size_t)(mbase + r0) * DMODEL + g0 * 8;
  const bf16u* Bg0 = Bt + (size_t)(nbase + r0) * DMODEL + g0 * 8;
  const bf16u* Ag1 = Ag0 + (size_t)64 * DMODEL;
  const bf16u* Bg1 = Bg0 + (size_t)64 * DMODEL;

  const int xq = (quad ^ (l15 & 3)) * 8;

  f32x4 acc[4][4];
#pragma unroll
  for (int i = 0; i < 4; ++i)
#pragma unroll
    for (int j = 0; j < 4; ++j) acc[i][j] = (f32x4){0.f, 0.f, 0.f, 0.f};

  load16_lds(Ag0, &As[0][tid * 8]);
  load16_lds(Ag1, &As[0][2048 + tid * 8]);
  load16_lds(Bg0, &Bs[0][tid * 8]);
  load16_lds(Bg1, &Bs[0][2048 + tid * 8]);

#pragma unroll 1
  for (int it = 0; it < 32; ++it) {
    const int cur = it & 1, nxt = cur ^ 1;
    if (it + 1 < 32) {
      const int kn = (it + 1) * 32;
      load16_lds(Ag0 + kn, &As[nxt][tid * 8]);
      load16_lds(Ag1 + kn, &As[nxt][2048 + tid * 8]);
      load16_lds(Bg0 + kn, &Bs[nxt][tid * 8]);
      load16_lds(Bg1 + kn, &Bs[nxt][2048 + tid * 8]);
      WAITCNT_VM(4);
    } else {
      WAITCNT_VM(0);
    }
    __builtin_amdgcn_s_barrier();
    u16x8 af[4], bfr[4];
#pragma unroll
    for (int i = 0; i < 4; ++i)
      af[i] = *(const u16x8*)&As[cur][(wrow + i * 16 + l15) * 32 + xq];
#pragma unroll
    for (int j = 0; j < 4; ++j)
      bfr[j] = *(const u16x8*)&Bs[cur][(wcol + j * 16 + l15) * 32 + xq];
#pragma unroll
    for (int i = 0; i < 4; ++i)
#pragma unroll
      for (int j = 0; j < 4; ++j)
        acc[i][j] = mfma_bf16(af[i], bfr[j], acc[i][j]);
    __builtin_amdgcn_s_barrier();
  }

#pragma unroll
  for (int i = 0; i < 4; ++i) {
    const int mrow = mbase + wrow + i * 16 + quad * 4;
    const int bb = mrow >> 11, ss = mrow & 2047;
#pragma unroll
    for (int j = 0; j < 4; ++j) {
      const int n = nbase + wcol + j * 16 + l15;
      const int h = n >> 6, hd = n & 63;
      if (vmode) {
        u16x4 pk;
#pragma unroll
        for (int r = 0; r < 4; ++r) pk[r] = f2b(acc[i][j][r]);
        *(u16x4*)&O[(((size_t)(bb * NH + h)) * HD + hd) * SEQ + ss] = pk;
      } else {
#pragma unroll
        for (int r = 0; r < 4; ++r)
          O[(((size_t)(bb * NH + h)) * SEQ + ss + r) * HD + hd] = f2b(acc[i][j][r] * smul);
      }
    }
  }
}

// ---------------- 64x128 bf16 MFMA GEMM, fp32-output, pipelined ----------------
// 64-row M-tile -> grid (8,128)=1024 blocks (4/CU) + 24 KB LDS: the latency-
// exposed 2-blocks/CU regime of the 128^2 version was the bottleneck.
__global__ __launch_bounds__(256) void gemm_out_kernel(const bf16u* __restrict__ A,
                                                       const bf16u* __restrict__ Bt,
                                                       float* __restrict__ Of) {
  __shared__ __align__(16) bf16u As[2][64 * 32];
  __shared__ __align__(16) bf16u Bs[2][128 * 32];

  const int tid = threadIdx.x;
  const int lane = tid & 63, quad = lane >> 4, l15 = lane & 15;
  const int wave = tid >> 6;
  const int wrow = (wave >> 1) * 32, wcol = (wave & 1) * 64;
  const int mbase = blockIdx.y * 64, nbase = blockIdx.x * 128;

  const int r0 = tid >> 2, s0 = tid & 3;
  const int g0 = s0 ^ (r0 & 3);
  const bf16u* Ag0 = A + (size_t)(mbase + r0) * DMODEL + g0 * 8;
  const bf16u* Bg0 = Bt + (size_t)(nbase + r0) * DMODEL + g0 * 8;
  const bf16u* Bg1 = Bg0 + (size_t)64 * DMODEL;

  const int xq = (quad ^ (l15 & 3)) * 8;

  f32x4 acc[2][4];
#pragma unroll
  for (int i = 0; i < 2; ++i)
#pragma unroll
    for (int j = 0; j < 4; ++j) acc[i][j] = (f32x4){0.f, 0.f, 0.f, 0.f};

  load16_lds(Ag0, &As[0][tid * 8]);
  load16_lds(Bg0, &Bs[0][tid * 8]);
  load16_lds(Bg1, &Bs[0][2048 + tid * 8]);

#pragma unroll 1
  for (int it = 0; it < 32; ++it) {
    const int cur = it & 1, nxt = cur ^ 1;
    if (it + 1 < 32) {
      const int kn = (it + 1) * 32;
      load16_lds(Ag0 + kn, &As[nxt][tid * 8]);
      load16_lds(Bg0 + kn, &Bs[nxt][tid * 8]);
      load16_lds(Bg1 + kn, &Bs[nxt][2048 + tid * 8]);
      WAITCNT_VM(3);
    } else {
      WAITCNT_VM(0);
    }
    __builtin_amdgcn_s_barrier();
    u16x8 af[2], bfr[4];
#pragma unroll
    for (int i = 0; i < 2; ++i)
      af[i] = *(const u16x8*)&As[cur][(wrow + i * 16 + l15) * 32 + xq];
#pragma unroll
    for (int j = 0; j < 4; ++j)
      bfr[j] = *(const u16x8*)&Bs[cur][(wcol + j * 16 + l15) * 32 + xq];
#pragma unroll
    for (int i = 0; i < 2; ++i)
#pragma unroll
      for (int j = 0; j < 4; ++j)
        acc[i][j] = mfma_bf16(af[i], bfr[j], acc[i][j]);
    __builtin_amdgcn_s_barrier();
  }

#pragma unroll
  for (int i = 0; i < 2; ++i) {
    const int mrow = mbase + wrow + i * 16 + quad * 4;
#pragma unroll
    for (int j = 0; j < 4; ++j) {
      const int n = nbase + wcol + j * 16 + l15;
#pragma unroll
      for (int r = 0; r < 4; ++r)
        Of[(size_t)(mrow + r) * DMODEL + n] = acc[i][j][r];
    }
  }
}

// ---------------- flash attention (causal), bf16 MFMA, v8 ----------------
// 1024 blocks (one 128-row q-tile each) with a CU-balanced qt table:
// CU hosts lids {c, c+256, c+512, c+768}; qt = tbl[lid>>8][(lid>>6)&3] has
// equal column sums (30) -> every CU gets 68 tile-units, all 4 blocks
// co-resident (LDS 35.8KB -> 4/CU, VGPR 84 -> 6 waves/SIMD). Avoids the
// v5/v6 mod-16 CU-aliasing trap while doubling waves/SIMD vs v7's 512 blocks.
// No running max; Q pre-scaled; row sums via MFMA ones-column; no shuffles.
__global__ __launch_bounds__(256, 2) void attn_kernel(const bf16u* __restrict__ Q,
                                                      const bf16u* __restrict__ K,
                                                      const bf16u* __restrict__ Vt,
                                                      bf16u* __restrict__ ctx) {
  const int lid = blockIdx.x + (blockIdx.y << 4);  // 0..1023
  const int kk = lid >> 8, slot = (lid >> 6) & 3, bh = lid & 63;
  int qt;
  if (kk == 0)      qt = slot;            // {0,1,2,3}
  else if (kk == 1) qt = 12 + (slot ^ 1); // {13,12,15,14}
  else if (kk == 2) qt = 7 - slot;        // {7,6,5,4}
  else              qt = 8 + (slot ^ 2);  // {10,11,8,9}

  const int b = bh >> 4, h = bh & 15;
  const size_t base = (size_t)bh * SEQ * HD;
  const bf16u* Qb = Q + base;
  const bf16u* Kb = K + base;
  const bf16u* Vb = Vt + base;  // [hd][s]

  const int tid = threadIdx.x;
  const int wave = tid >> 6, lane = tid & 63, quad = lane >> 4, l15 = lane & 15;
  const int qrow0 = qt * 128 + wave * 32;
  const int ntiles = 2 * qt + 2;

  __shared__ __align__(16) bf16u Ks[64 * 72];     // [key][hd]
  __shared__ __align__(16) bf16u Vs[64 * 72];     // [hd][key]
  __shared__ __align__(16) bf16u Ps[4][32 * 68];  // per-wave P scratch

  const int srow = tid >> 3;       // 0..31
  const int scol = (tid & 7) * 8;  // 0..56

  u16x8 ones;
#pragma unroll
  for (int i = 0; i < 8; ++i) ones[i] = 0x3F80;  // bf16 1.0

  u16x8 aq[2][2];
#pragma unroll
  for (int rt = 0; rt < 2; ++rt)
#pragma unroll
    for (int ch = 0; ch < 2; ++ch)
      aq[rt][ch] = *(const u16x8*)(Qb + (size_t)(qrow0 + rt * 16 + l15) * HD + ch * 32 + quad * 8);

  f32x4 acc[2][4], accl[2];
#pragma unroll
  for (int rt = 0; rt < 2; ++rt) {
#pragma unroll
    for (int nc = 0; nc < 4; ++nc) acc[rt][nc] = (f32x4){0.f, 0.f, 0.f, 0.f};
    accl[rt] = (f32x4){0.f, 0.f, 0.f, 0.f};
  }

  u16x8 kr0 = *(const u16x8*)(Kb + (size_t)srow * HD + scol);
  u16x8 kr1 = *(const u16x8*)(Kb + (size_t)(srow + 32) * HD + scol);
  u16x8 vr0 = *(const u16x8*)(Vb + (size_t)srow * SEQ + scol);
  u16x8 vr1 = *(const u16x8*)(Vb + (size_t)(srow + 32) * SEQ + scol);

#pragma unroll 1
  for (int kt = 0; kt < ntiles; ++kt) {
    const int kbase = kt * 64;
    __syncthreads();
    *(u16x8*)&Ks[srow * 72 + scol] = kr0;
    *(u16x8*)&Ks[(srow + 32) * 72 + scol] = kr1;
    *(u16x8*)&Vs[srow * 72 + scol] = vr0;
    *(u16x8*)&Vs[(srow + 32) * 72 + scol] = vr1;
    __syncthreads();
    if (kt + 1 < ntiles) {
      const int nb = kbase + 64;
      kr0 = *(const u16x8*)(Kb + (size_t)(nb + srow) * HD + scol);
      kr1 = *(const u16x8*)(Kb + (size_t)(nb + srow + 32) * HD + scol);
      vr0 = *(const u16x8*)(Vb + (size_t)srow * SEQ + nb + scol);
      vr1 = *(const u16x8*)(Vb + (size_t)(srow + 32) * SEQ + nb + scol);
    }
    if (kbase > qrow0 + 31) continue;  // fully masked for this wave

    // QK^T: 32 rows x 64 keys (Q pre-scaled: scores log2-domain ready)
    f32x4 sc[2][4];
#pragma unroll
    for (int ct = 0; ct < 4; ++ct) {
      u16x8 bk0 = *(const u16x8*)&Ks[(ct * 16 + l15) * 72 + quad * 8];
      u16x8 bk1 = *(const u16x8*)&Ks[(ct * 16 + l15) * 72 + 32 + quad * 8];
#pragma unroll
      for (int rt = 0; rt < 2; ++rt) {
        f32x4 z = {0.f, 0.f, 0.f, 0.f};
        z = mfma_bf16(aq[rt][0], bk0, z);
        z = mfma_bf16(aq[rt][1], bk1, z);
        sc[rt][ct] = z;
      }
    }

    const bool needmask = (kbase + 63 > qrow0);
#pragma unroll
    for (int rt = 0; rt < 2; ++rt) {
#pragma unroll
      for (int r = 0; r < 4; ++r) {
        const int row = qrow0 + rt * 16 + quad * 4 + r;
        float e0 = exp2f(sc[rt][0][r]);
        float e1 = exp2f(sc[rt][1][r]);
        float e2 = exp2f(sc[rt][2][r]);
        float e3 = exp2f(sc[rt][3][r]);
        if (needmask) {
          if (kbase + l15 > row) e0 = 0.f;
          if (kbase + 16 + l15 > row) e1 = 0.f;
          if (kbase + 32 + l15 > row) e2 = 0.f;
          if (kbase + 48 + l15 > row) e3 = 0.f;
        }
        const int prow = (rt * 16 + quad * 4 + r) * 68;
        Ps[wave][prow + l15] = f2b(e0);
        Ps[wave][prow + 16 + l15] = f2b(e1);
        Ps[wave][prow + 32 + l15] = f2b(e2);
        Ps[wave][prow + 48 + l15] = f2b(e3);
      }
    }

    // P: C-layout -> LDS -> A-layout (same-wave readback, no barrier)
    u16x8 pa[2][2];
#pragma unroll
    for (int rt = 0; rt < 2; ++rt)
#pragma unroll
      for (int ch = 0; ch < 2; ++ch)
        pa[rt][ch] = *(const u16x8*)&Ps[wave][(rt * 16 + l15) * 68 + ch * 32 + quad * 8];

#pragma unroll
    for (int nc = 0; nc < 4; ++nc) {
      u16x8 bv0 = *(const u16x8*)&Vs[(nc * 16 + l15) * 72 + quad * 8];
      u16x8 bv1 = *(const u16x8*)&Vs[(nc * 16 + l15) * 72 + 32 + quad * 8];
#pragma unroll
      for (int rt = 0; rt < 2; ++rt) {
        acc[rt][nc] = mfma_bf16(pa[rt][0], bv0, acc[rt][nc]);
        acc[rt][nc] = mfma_bf16(pa[rt][1], bv1, acc[rt][nc]);
      }
    }
#pragma unroll
    for (int rt = 0; rt < 2; ++rt) {
      accl[rt] = mfma_bf16(pa[rt][0], ones, accl[rt]);
      accl[rt] = mfma_bf16(pa[rt][1], ones, accl[rt]);
    }
  }

  // epilogue: normalize, write ctx[b][s][h*64+hd] bf16
#pragma unroll
  for (int rt = 0; rt < 2; ++rt) {
#pragma unroll
    for (int r = 0; r < 4; ++r) {
      const float inv = 1.0f / accl[rt][r];
      const int row = qrow0 + rt * 16 + quad * 4 + r;
      const size_t o = ((size_t)b * SEQ + row) * DMODEL + h * HD;
#pragma unroll
      for (int nc = 0; nc < 4; ++nc)
        ctx[o + nc * 16 + l15] = f2b(acc[rt][nc][r] * inv);
    }
  }
}

extern "C" void kernel_launch(void* const* d_in, const int* in_sizes, int n_in,
                              void* d_out, int out_size, void* d_ws, size_t ws_size,
                              hipStream_t stream) {
  const float* x  = (const float*)d_in[0];
  const float* Wq = (const float*)d_in[1];
  const float* Wk = (const float*)d_in[2];
  const float* Wv = (const float*)d_in[3];
  const float* Wo = (const float*)d_in[4];
  float* out = (float*)d_out;

  char* ws = (char*)d_ws;
  const size_t MK = (size_t)8192 * DMODEL;
  const size_t WW = (size_t)DMODEL * DMODEL;
  bf16u* xb  = (bf16u*)ws;
  bf16u* Wt  = (bf16u*)(ws + MK * 2);
  bf16u* QKV = (bf16u*)(ws + MK * 2 + 4 * WW * 2);
  bf16u* Cx  = (bf16u*)(ws + MK * 2 + 4 * WW * 2 + 3 * MK * 2);

  const int n4 = (int)(MK / 4);
  cast_x_kernel<<<dim3(n4 / 256), 256, 0, stream>>>((const float4*)x, (u16x4*)xb, n4);
  transpose_w_kernel<<<dim3(32, 32, 4), dim3(32, 8), 0, stream>>>(Wq, Wk, Wv, Wo, Wt);
  gemm_qkv_kernel<<<dim3(8, 64, 3), 256, 0, stream>>>(xb, Wt, QKV);
  attn_kernel<<<dim3(16, 64), 256, 0, stream>>>(QKV, QKV + MK, QKV + 2 * MK, Cx);
  gemm_out_kernel<<<dim3(8, 128), 256, 0, stream>>>(Cx, Wt + 3 * WW, out);
}